// Round 1
// 425.213 us; speedup vs baseline: 1.0563x; 1.0563x over previous
//
#include <hip/hip_runtime.h>
#include <hip/hip_bf16.h>

#define NTIME   2000
#define NBATCH  128
#define INSIZE  256
#define NOUT    40
#define NROWS   (NTIME * NBATCH)   // 256000
#define CCHUNK  80                 // parallel-scan chunks
#define LSTEP   25                 // steps per chunk; CCHUNK*LSTEP == NTIME

typedef __attribute__((ext_vector_type(8))) short  short8;   // 8 bf16 = 4 VGPRs
typedef __attribute__((ext_vector_type(4))) float  float4v;

#define L2E 1.4426950408889634f
#define LN2 0.6931471805599453f

__device__ __forceinline__ float fexp2(float x){ return __builtin_amdgcn_exp2f(x); } // v_exp_f32 (2^x)
__device__ __forceinline__ float flog2(float x){ return __builtin_amdgcn_logf(x);  } // v_log_f32 (log2)

// fp32 -> bf16 with round-to-nearest-even (bit arithmetic; no lib call)
__device__ __forceinline__ short f2bf(float f) {
    unsigned u = __float_as_uint(f);
    unsigned r = u + 0x7fffu + ((u >> 16) & 1u);
    return (short)(r >> 16);
}

// ---------------------------------------------------------------- prep: W fp32 -> bf16, padded 48x256
__global__ __launch_bounds__(256) void prep_w(const float* __restrict__ W,
                                              short* __restrict__ Wb)
{
    int idx = blockIdx.x * 256 + threadIdx.x;   // 48*256 = 12288
    int n = idx >> 8, k = idx & 255;
    float v = (n < NOUT) ? W[n * INSIZE + k] : 0.f;
    Wb[idx] = f2bf(v);
}

// ---------------------------------------------------------------- GEMM + activations
// block = 256 threads = 4 waves; block computes 128 rows x all 40 outputs.
// wave w: rows [blk*128 + w*32, +32), as 2 m-tiles of 16; 3 n-tiles of 16 (48 padded).
__global__ __launch_bounds__(256) void gemm_act(const float* __restrict__ x,
                                                const short* __restrict__ Wb,
                                                const float* __restrict__ bias,
                                                float* __restrict__ out)
{
    const int tid  = threadIdx.x;
    const int wave = tid >> 6, lane = tid & 63;
    const int l16  = lane & 15, quad = lane >> 4;
    const long rowBase = (long)blockIdx.x * 128 + wave * 32;

    float4v acc[2][3];
#pragma unroll
    for (int mi = 0; mi < 2; ++mi)
#pragma unroll
        for (int ni = 0; ni < 3; ++ni)
            acc[mi][ni] = (float4v){0.f, 0.f, 0.f, 0.f};

    const float* xp0 = x + (rowBase + l16) * (long)INSIZE + quad * 8;
    const float* xp1 = xp0 + 16 * INSIZE;
    const short* wp = Wb + l16 * INSIZE + quad * 8;

#pragma unroll
    for (int s = 0; s < 8; ++s) {          // K = 256 = 8 stages of 32
        short8 afrag[2];
#pragma unroll
        for (int mi = 0; mi < 2; ++mi) {
            const float* xp = (mi ? xp1 : xp0) + s * 32;
            float4v xa = *(const float4v*)xp;
            float4v xb = *(const float4v*)(xp + 4);
            short8 a;
            a[0] = f2bf(xa[0]); a[1] = f2bf(xa[1]); a[2] = f2bf(xa[2]); a[3] = f2bf(xa[3]);
            a[4] = f2bf(xb[0]); a[5] = f2bf(xb[1]); a[6] = f2bf(xb[2]); a[7] = f2bf(xb[3]);
            afrag[mi] = a;
        }
#pragma unroll
        for (int ni = 0; ni < 3; ++ni) {
            short8 bfrag = *(const short8*)(wp + ni * 16 * INSIZE + s * 32);
            acc[0][ni] = __builtin_amdgcn_mfma_f32_16x16x32_bf16(afrag[0], bfrag, acc[0][ni], 0, 0, 0);
            acc[1][ni] = __builtin_amdgcn_mfma_f32_16x16x32_bf16(afrag[1], bfrag, acc[1][ni], 0, 0, 0);
        }
    }

    // epilogue: C/D layout col = lane&15, row = quad*4 + reg
#pragma unroll
    for (int mi = 0; mi < 2; ++mi) {
        long row0 = rowBase + mi * 16 + quad * 4;
#pragma unroll
        for (int ni = 0; ni < 3; ++ni) {
            int o = ni * 16 + l16;
            if (o >= NOUT) continue;
            float bv = bias[o];
#pragma unroll
            for (int r = 0; r < 4; ++r) {
                float y = acc[mi][ni][r] + bv;
                float val;
                if (o < 8) {
                    // softplus(y) = max(y,0) + ln2*log2(1 + 2^(-|y|*log2e))
                    float sp = fmaxf(y, 0.f) + LN2 * flog2(1.f + fexp2(-fabsf(y) * L2E));
                    val = (o < 4 ? 1.0f : 0.1f) + sp;
                } else {
                    float e = fexp2(2.f * fabsf(y) * L2E);    // e^{2|y|}
                    float t = 1.f - 2.f / (e + 1.f);
                    val = 5.f * copysignf(t, y);
                }
                out[(row0 + r) * NOUT + o] = val;
            }
        }
    }
}

// ---------------------------------------------------------------- chunked parallel scan (log-semiring)
// 8 lanes per (batch, chunk): lane j0 carries column j0 of the chunk's 8x8 matrix.
// base-2 domain: g = f*log2e; u = w*log2e folded into the fma.
// scan_step: consume w (32 fma's first), then reload w for step+2 (2-deep pipeline),
// then do the LSE work while the reload is in flight.
__device__ __forceinline__ void scan_step(float (&m)[8], float4v (&w)[8], const float* reload)
{
    const float* wv = (const float*)&w[0];
    float sa[4][8];
#pragma unroll
    for (int i = 0; i < 4; ++i)
#pragma unroll
        for (int k = 0; k < 8; ++k) sa[i][k] = fmaf(wv[i * 8 + k], L2E, m[k]);
    // w is now dead: reload it with step+2's data (addresses independent of compute,
    // ~2 steps of LSE work below to hide L3/remote-L2 latency)
#pragma unroll
    for (int q = 0; q < 8; ++q) w[q] = *(const float4v*)(reload + q * 4);

    float nm[8];
#pragma unroll
    for (int i = 0; i < 4; ++i) {
        float* s = sa[i];
        // stay: sources {i, i+4}
        float a = s[i], b2 = s[i + 4];
        float mx2 = fmaxf(a, b2), mn2 = fminf(a, b2);
        nm[4 + i] = mx2 + flog2(1.f + fexp2(mn2 - mx2));
        // move: the other 6 sources (mask and LSE over 8; -1e30 absorbs safely in fp32)
        s[i] = -1e30f; s[i + 4] = -1e30f;
        float mx = fmaxf(fmaxf(fmaxf(s[0], s[1]), fmaxf(s[2], s[3])),
                         fmaxf(fmaxf(s[4], s[5]), fmaxf(s[6], s[7])));
        float sum = ((fexp2(s[0] - mx) + fexp2(s[1] - mx)) + (fexp2(s[2] - mx) + fexp2(s[3] - mx)))
                  + ((fexp2(s[4] - mx) + fexp2(s[5] - mx)) + (fexp2(s[6] - mx) + fexp2(s[7] - mx)));
        nm[i] = mx + flog2(sum);
    }
#pragma unroll
    for (int i = 0; i < 8; ++i) m[i] = nm[i];
}

__global__ __launch_bounds__(256) void scan_chunks(const float* __restrict__ out,
                                                   float* __restrict__ chunkM)
{
    const int tid   = threadIdx.x;
    const int g     = tid >> 3, j0 = tid & 7;
    const int c     = blockIdx.x >> 2;                    // 4 blocks per chunk
    const int batch = ((blockIdx.x & 3) << 5) + g;        // 32 batches per block
    const int t0    = c * LSTEP;

    float m[8];
#pragma unroll
    for (int i = 0; i < 8; ++i) m[i] = (i == j0) ? 0.f : -1e30f;

    const size_t R = (size_t)NBATCH * NOUT;
    const float* base = out + ((size_t)(t0 * NBATCH + batch) * NOUT + 8);

    float4v wA[8], wB[8];               // double-buffer: wA = even steps, wB = odd steps
#pragma unroll
    for (int q = 0; q < 8; ++q) wA[q] = *(const float4v*)(base + q * 4);
#pragma unroll
    for (int q = 0; q < 8; ++q) wB[q] = *(const float4v*)(base + R + q * 4);

    // steps 0..23 as 12 double-steps; each scan_step reloads its buffer with step+2
    for (int it = 0; it < (LSTEP - 1) / 2; ++it) {
        scan_step(m, wA, base + (size_t)(2 * it + 2) * R);                 // step 2it  (reload 2it+2 <= 24: valid)
        const float* pB = (2 * it + 3 < LSTEP) ? base + (size_t)(2 * it + 3) * R
                                               : base;                     // clamped dummy (never consumed)
        scan_step(m, wB, pB);                                              // step 2it+1
    }
    scan_step(m, wA, base);             // step 24 (final; dummy reload from base, unused)

    float* dst = chunkM + (((size_t)batch * CCHUNK + c) * 8 + j0) * 8;
#pragma unroll
    for (int i = 0; i < 8; ++i) dst[i] = m[i];
}

// ---------------------------------------------------------------- sequential combine over chunks
// 4 blocks x 256 threads (spread over 4 CUs). 4-deep static prefetch pipeline:
// loads for chunk c+4 issue ~3 iterations before use, hiding L3/remote-L2 latency.
#define COMB1(P, CN)                                                                         \
    {                                                                                        \
        float s_[8];                                                                         \
        _Pragma("unroll") for (int j = 0; j < 8; ++j) s_[j] = P[j] + v[j];                   \
        int cl_ = ((CN) < CCHUNK) ? (CN) : (CCHUNK - 1);                                     \
        const float* Mp_ = Mb + (size_t)cl_ * 64 + ip;                                       \
        _Pragma("unroll") for (int j = 0; j < 8; ++j) P[j] = Mp_[j * 8];                     \
        float mx_ = fmaxf(fmaxf(fmaxf(s_[0], s_[1]), fmaxf(s_[2], s_[3])),                   \
                          fmaxf(fmaxf(s_[4], s_[5]), fmaxf(s_[6], s_[7])));                  \
        float sum_ = ((fexp2(s_[0] - mx_) + fexp2(s_[1] - mx_)) +                            \
                      (fexp2(s_[2] - mx_) + fexp2(s_[3] - mx_)))                             \
                   + ((fexp2(s_[4] - mx_) + fexp2(s_[5] - mx_)) +                            \
                      (fexp2(s_[6] - mx_) + fexp2(s_[7] - mx_)));                            \
        float nv_ = mx_ + flog2(sum_);                                                       \
        _Pragma("unroll") for (int j = 0; j < 8; ++j) v[j] = __shfl(nv_, gbase + j, 64);     \
    }

__global__ __launch_bounds__(256) void combine_k(const float* __restrict__ chunkM,
                                                 float* __restrict__ logZdiv)
{
    const int tid   = blockIdx.x * 256 + threadIdx.x;   // 128 batches * 8 lanes = 1024
    const int ip    = tid & 7;
    const int batch = tid >> 3;
    const int gbase = (threadIdx.x & 63) & ~7;          // group base lane within wave

    const float* Mb = chunkM + ((size_t)batch * CCHUNK) * 64;

    float v[8];
#pragma unroll
    for (int j = 0; j < 8; ++j) v[j] = 0.f;   // fwd0 = zeros

    float P0[8], P1[8], P2[8], P3[8];
#pragma unroll
    for (int j = 0; j < 8; ++j) P0[j] = Mb[0 * 64 + j * 8 + ip];
#pragma unroll
    for (int j = 0; j < 8; ++j) P1[j] = Mb[1 * 64 + j * 8 + ip];
#pragma unroll
    for (int j = 0; j < 8; ++j) P2[j] = Mb[2 * 64 + j * 8 + ip];
#pragma unroll
    for (int j = 0; j < 8; ++j) P3[j] = Mb[3 * 64 + j * 8 + ip];

    for (int c = 0; c < CCHUNK; c += 4) {     // CCHUNK = 80 = 4*20 exact
        COMB1(P0, c + 4)
        COMB1(P1, c + 5)
        COMB1(P2, c + 6)
        COMB1(P3, c + 7)
    }

    float mx = fmaxf(fmaxf(fmaxf(v[0], v[1]), fmaxf(v[2], v[3])),
                     fmaxf(fmaxf(v[4], v[5]), fmaxf(v[6], v[7])));
    float sum = ((fexp2(v[0] - mx) + fexp2(v[1] - mx)) + (fexp2(v[2] - mx) + fexp2(v[3] - mx)))
              + ((fexp2(v[4] - mx) + fexp2(v[5] - mx)) + (fexp2(v[6] - mx) + fexp2(v[7] - mx)));
    float r = mx + flog2(sum);
    if (ip == 0) logZdiv[batch] = r * LN2 / (float)NTIME;   // back to base-e, /ntime
}

// ---------------------------------------------------------------- subtract logZ from trans section
__global__ __launch_bounds__(256) void sub_logz(float* __restrict__ out,
                                                const float* __restrict__ logZdiv)
{
    size_t idx = (size_t)blockIdx.x * 256 + threadIdx.x;   // 2000*128*8 float4s
    size_t row = idx >> 3;
    int q = (int)(idx & 7);
    int batch = (int)(row & 127);
    float lz = logZdiv[batch];
    float4v* pp = (float4v*)(out + row * NOUT + 8 + q * 4);
    float4v vv = *pp;
    vv[0] -= lz; vv[1] -= lz; vv[2] -= lz; vv[3] -= lz;
    *pp = vv;
}

// ---------------------------------------------------------------- launch
extern "C" void kernel_launch(void* const* d_in, const int* in_sizes, int n_in,
                              void* d_out, int out_size, void* d_ws, size_t ws_size,
                              hipStream_t stream)
{
    const float* x = (const float*)d_in[0];   // (2000,128,256)
    const float* W = (const float*)d_in[1];   // (40,256)
    const float* b = (const float*)d_in[2];   // (40,)
    float* out = (float*)d_out;               // (2000,128,40)

    char* ws = (char*)d_ws;
    short* Wb      = (short*)ws;                                                 // 24576 B
    float* chunkM  = (float*)(ws + 32768);                                       // 128*80*64*4 = 2621440 B
    float* logZdiv = (float*)(ws + 32768 + (size_t)NBATCH * CCHUNK * 64 * 4);

    hipLaunchKernelGGL(prep_w,      dim3(48),        dim3(256), 0, stream, W, Wb);
    hipLaunchKernelGGL(gemm_act,    dim3(NROWS/128), dim3(256), 0, stream, x, Wb, b, out);
    hipLaunchKernelGGL(scan_chunks, dim3(CCHUNK*4),  dim3(256), 0, stream, out, chunkM);
    hipLaunchKernelGGL(combine_k,   dim3(4),         dim3(256), 0, stream, chunkM, logZdiv);
    hipLaunchKernelGGL(sub_logz,    dim3(8000),      dim3(256), 0, stream, out, logZdiv);
}

// Round 3
// 424.491 us; speedup vs baseline: 1.0581x; 1.0017x over previous
//
#include <hip/hip_runtime.h>
#include <hip/hip_bf16.h>

#define NTIME   2000
#define NBATCH  128
#define INSIZE  256
#define NOUT    40
#define NROWS   (NTIME * NBATCH)   // 256000
#define CCHUNK  80                 // parallel-scan chunks
#define LSTEP   25                 // steps per chunk; CCHUNK*LSTEP == NTIME

typedef __attribute__((ext_vector_type(8))) short  short8;   // 8 bf16 = 4 VGPRs
typedef __attribute__((ext_vector_type(4))) float  float4v;

#define L2E 1.4426950408889634f
#define LN2 0.6931471805599453f

__device__ __forceinline__ float fexp2(float x){ return __builtin_amdgcn_exp2f(x); } // v_exp_f32 (2^x)
__device__ __forceinline__ float flog2(float x){ return __builtin_amdgcn_logf(x);  } // v_log_f32 (log2)

// fp32 -> bf16 with round-to-nearest-even (bit arithmetic; no lib call)
__device__ __forceinline__ short f2bf(float f) {
    unsigned u = __float_as_uint(f);
    unsigned r = u + 0x7fffu + ((u >> 16) & 1u);
    return (short)(r >> 16);
}

// ---------------------------------------------------------------- GEMM + activations (W converted inline)
// block = 256 threads = 4 waves; block computes 128 rows x all 40 outputs.
// wave w: rows [blk*128 + w*32, +32), as 2 m-tiles of 16; 3 n-tiles of 16 (48 padded).
// W is read as fp32 directly (L2-resident broadcast, hidden under the x HBM shadow)
// and converted to bf16 in-register -- removes the prep_w kernel + launch gap.
__global__ __launch_bounds__(256) void gemm_act(const float* __restrict__ x,
                                                const float* __restrict__ W,
                                                const float* __restrict__ bias,
                                                float* __restrict__ out)
{
    const int tid  = threadIdx.x;
    const int wave = tid >> 6, lane = tid & 63;
    const int l16  = lane & 15, quad = lane >> 4;
    const long rowBase = (long)blockIdx.x * 128 + wave * 32;

    float4v acc[2][3];
#pragma unroll
    for (int mi = 0; mi < 2; ++mi)
#pragma unroll
        for (int ni = 0; ni < 3; ++ni)
            acc[mi][ni] = (float4v){0.f, 0.f, 0.f, 0.f};

    const float* xp0 = x + (rowBase + l16) * (long)INSIZE + quad * 8;
    const float* xp1 = xp0 + 16 * INSIZE;

    // per-ni W row pointer + pad mask (row >= 40 is zero padding; clamp addr, mask value)
    const float* wrow[3];
    float        wmsk[3];
#pragma unroll
    for (int ni = 0; ni < 3; ++ni) {
        int row = ni * 16 + l16;
        wrow[ni] = W + (long)(row < NOUT ? row : 0) * INSIZE + quad * 8;
        wmsk[ni] = (row < NOUT) ? 1.f : 0.f;
    }

#pragma unroll
    for (int s = 0; s < 8; ++s) {          // K = 256 = 8 stages of 32
        short8 afrag[2];
#pragma unroll
        for (int mi = 0; mi < 2; ++mi) {
            const float* xp = (mi ? xp1 : xp0) + s * 32;
            float4v xa = *(const float4v*)xp;
            float4v xb = *(const float4v*)(xp + 4);
            short8 a;
            a[0] = f2bf(xa[0]); a[1] = f2bf(xa[1]); a[2] = f2bf(xa[2]); a[3] = f2bf(xa[3]);
            a[4] = f2bf(xb[0]); a[5] = f2bf(xb[1]); a[6] = f2bf(xb[2]); a[7] = f2bf(xb[3]);
            afrag[mi] = a;
        }
#pragma unroll
        for (int ni = 0; ni < 3; ++ni) {
            const float* wp = wrow[ni] + s * 32;
            float m = wmsk[ni];
            float4v wa = *(const float4v*)wp;
            float4v wb = *(const float4v*)(wp + 4);
            short8 bfrag;
            bfrag[0] = f2bf(wa[0] * m); bfrag[1] = f2bf(wa[1] * m);
            bfrag[2] = f2bf(wa[2] * m); bfrag[3] = f2bf(wa[3] * m);
            bfrag[4] = f2bf(wb[0] * m); bfrag[5] = f2bf(wb[1] * m);
            bfrag[6] = f2bf(wb[2] * m); bfrag[7] = f2bf(wb[3] * m);
            acc[0][ni] = __builtin_amdgcn_mfma_f32_16x16x32_bf16(afrag[0], bfrag, acc[0][ni], 0, 0, 0);
            acc[1][ni] = __builtin_amdgcn_mfma_f32_16x16x32_bf16(afrag[1], bfrag, acc[1][ni], 0, 0, 0);
        }
    }

    // epilogue: C/D layout col = lane&15, row = quad*4 + reg
#pragma unroll
    for (int mi = 0; mi < 2; ++mi) {
        long row0 = rowBase + mi * 16 + quad * 4;
#pragma unroll
        for (int ni = 0; ni < 3; ++ni) {
            int o = ni * 16 + l16;
            if (o >= NOUT) continue;
            float bv = bias[o];
#pragma unroll
            for (int r = 0; r < 4; ++r) {
                float y = acc[mi][ni][r] + bv;
                float val;
                if (o < 8) {
                    // softplus(y) = max(y,0) + ln2*log2(1 + 2^(-|y|*log2e))
                    float sp = fmaxf(y, 0.f) + LN2 * flog2(1.f + fexp2(-fabsf(y) * L2E));
                    val = (o < 4 ? 1.0f : 0.1f) + sp;
                } else {
                    float e = fexp2(2.f * fabsf(y) * L2E);    // e^{2|y|}
                    float t = 1.f - 2.f / (e + 1.f);
                    val = 5.f * copysignf(t, y);
                }
                out[(row0 + r) * NOUT + o] = val;
            }
        }
    }
}

// ---------------------------------------------------------------- chunked parallel scan (log-semiring)
// 8 lanes per (batch, chunk): lane j0 carries column j0 of the chunk's 8x8 matrix.
// base-2 domain: g = f*log2e; u = w*log2e folded into the fma.
// scan_step: consume w (32 fma's first), then reload w for step+2 (2-deep pipeline),
// then do the LSE work while the reload is in flight.
__device__ __forceinline__ void scan_step(float (&m)[8], float4v (&w)[8], const float* reload)
{
    const float* wv = (const float*)&w[0];
    float sa[4][8];
#pragma unroll
    for (int i = 0; i < 4; ++i)
#pragma unroll
        for (int k = 0; k < 8; ++k) sa[i][k] = fmaf(wv[i * 8 + k], L2E, m[k]);
    // w is now dead: reload it with step+2's data (addresses independent of compute)
#pragma unroll
    for (int q = 0; q < 8; ++q) w[q] = *(const float4v*)(reload + q * 4);

    float nm[8];
#pragma unroll
    for (int i = 0; i < 4; ++i) {
        float* s = sa[i];
        // stay: sources {i, i+4}
        float a = s[i], b2 = s[i + 4];
        float mx2 = fmaxf(a, b2), mn2 = fminf(a, b2);
        nm[4 + i] = mx2 + flog2(1.f + fexp2(mn2 - mx2));
        // move: the other 6 sources (mask and LSE over 8; -1e30 absorbs safely in fp32)
        s[i] = -1e30f; s[i + 4] = -1e30f;
        float mx = fmaxf(fmaxf(fmaxf(s[0], s[1]), fmaxf(s[2], s[3])),
                         fmaxf(fmaxf(s[4], s[5]), fmaxf(s[6], s[7])));
        float sum = ((fexp2(s[0] - mx) + fexp2(s[1] - mx)) + (fexp2(s[2] - mx) + fexp2(s[3] - mx)))
                  + ((fexp2(s[4] - mx) + fexp2(s[5] - mx)) + (fexp2(s[6] - mx) + fexp2(s[7] - mx)));
        nm[i] = mx + flog2(sum);
    }
#pragma unroll
    for (int i = 0; i < 8; ++i) m[i] = nm[i];
}

__global__ __launch_bounds__(256) void scan_chunks(const float* __restrict__ out,
                                                   float* __restrict__ chunkM)
{
    const int tid   = threadIdx.x;
    const int g     = tid >> 3, j0 = tid & 7;
    const int c     = blockIdx.x >> 2;                    // 4 blocks per chunk
    const int batch = ((blockIdx.x & 3) << 5) + g;        // 32 batches per block
    const int t0    = c * LSTEP;

    float m[8];
#pragma unroll
    for (int i = 0; i < 8; ++i) m[i] = (i == j0) ? 0.f : -1e30f;

    const size_t R = (size_t)NBATCH * NOUT;
    const float* base = out + ((size_t)(t0 * NBATCH + batch) * NOUT + 8);

    float4v wA[8], wB[8];               // double-buffer: wA = even steps, wB = odd steps
#pragma unroll
    for (int q = 0; q < 8; ++q) wA[q] = *(const float4v*)(base + q * 4);
#pragma unroll
    for (int q = 0; q < 8; ++q) wB[q] = *(const float4v*)(base + R + q * 4);

    // steps 0..23 as 12 double-steps; each scan_step reloads its buffer with step+2
    for (int it = 0; it < (LSTEP - 1) / 2; ++it) {
        scan_step(m, wA, base + (size_t)(2 * it + 2) * R);                 // step 2it  (reload 2it+2 <= 24: valid)
        const float* pB = (2 * it + 3 < LSTEP) ? base + (size_t)(2 * it + 3) * R
                                               : base;                     // clamped dummy (never consumed)
        scan_step(m, wB, pB);                                              // step 2it+1
    }
    scan_step(m, wA, base);             // step 24 (final; dummy reload from base, unused)

    float* dst = chunkM + (((size_t)batch * CCHUNK + c) * 8 + j0) * 8;
#pragma unroll
    for (int i = 0; i < 8; ++i) dst[i] = m[i];
}

// ---------------------------------------------------------------- sequential combine over chunks
// 4 blocks x 256 threads (spread over 4 CUs). 4-deep static prefetch pipeline:
// loads for chunk c+4 issue ~3 iterations before use, hiding L3/remote-L2 latency.
#define COMB1(P, CN)                                                                         \
    {                                                                                        \
        float s_[8];                                                                         \
        _Pragma("unroll") for (int j = 0; j < 8; ++j) s_[j] = P[j] + v[j];                   \
        int cl_ = ((CN) < CCHUNK) ? (CN) : (CCHUNK - 1);                                     \
        const float* Mp_ = Mb + (size_t)cl_ * 64 + ip;                                       \
        _Pragma("unroll") for (int j = 0; j < 8; ++j) P[j] = Mp_[j * 8];                     \
        float mx_ = fmaxf(fmaxf(fmaxf(s_[0], s_[1]), fmaxf(s_[2], s_[3])),                   \
                          fmaxf(fmaxf(s_[4], s_[5]), fmaxf(s_[6], s_[7])));                  \
        float sum_ = ((fexp2(s_[0] - mx_) + fexp2(s_[1] - mx_)) +                            \
                      (fexp2(s_[2] - mx_) + fexp2(s_[3] - mx_)))                             \
                   + ((fexp2(s_[4] - mx_) + fexp2(s_[5] - mx_)) +                            \
                      (fexp2(s_[6] - mx_) + fexp2(s_[7] - mx_)));                            \
        float nv_ = mx_ + flog2(sum_);                                                       \
        _Pragma("unroll") for (int j = 0; j < 8; ++j) v[j] = __shfl(nv_, gbase + j, 64);     \
    }

__global__ __launch_bounds__(256) void combine_k(const float* __restrict__ chunkM,
                                                 float* __restrict__ logZdiv)
{
    const int tid   = blockIdx.x * 256 + threadIdx.x;   // 128 batches * 8 lanes = 1024
    const int ip    = tid & 7;
    const int batch = tid >> 3;
    const int gbase = (threadIdx.x & 63) & ~7;          // group base lane within wave

    const float* Mb = chunkM + ((size_t)batch * CCHUNK) * 64;

    float v[8];
#pragma unroll
    for (int j = 0; j < 8; ++j) v[j] = 0.f;   // fwd0 = zeros

    float P0[8], P1[8], P2[8], P3[8];
#pragma unroll
    for (int j = 0; j < 8; ++j) P0[j] = Mb[0 * 64 + j * 8 + ip];
#pragma unroll
    for (int j = 0; j < 8; ++j) P1[j] = Mb[1 * 64 + j * 8 + ip];
#pragma unroll
    for (int j = 0; j < 8; ++j) P2[j] = Mb[2 * 64 + j * 8 + ip];
#pragma unroll
    for (int j = 0; j < 8; ++j) P3[j] = Mb[3 * 64 + j * 8 + ip];

    for (int c = 0; c < CCHUNK; c += 4) {     // CCHUNK = 80 = 4*20 exact
        COMB1(P0, c + 4)
        COMB1(P1, c + 5)
        COMB1(P2, c + 6)
        COMB1(P3, c + 7)
    }

    float mx = fmaxf(fmaxf(fmaxf(v[0], v[1]), fmaxf(v[2], v[3])),
                     fmaxf(fmaxf(v[4], v[5]), fmaxf(v[6], v[7])));
    float sum = ((fexp2(v[0] - mx) + fexp2(v[1] - mx)) + (fexp2(v[2] - mx) + fexp2(v[3] - mx)))
              + ((fexp2(v[4] - mx) + fexp2(v[5] - mx)) + (fexp2(v[6] - mx) + fexp2(v[7] - mx)));
    float r = mx + flog2(sum);
    if (ip == 0) logZdiv[batch] = r * LN2 / (float)NTIME;   // back to base-e, /ntime
}

// ---------------------------------------------------------------- subtract logZ from trans section
__global__ __launch_bounds__(256) void sub_logz(float* __restrict__ out,
                                                const float* __restrict__ logZdiv)
{
    size_t idx = (size_t)blockIdx.x * 256 + threadIdx.x;   // 2000*128*8 float4s
    size_t row = idx >> 3;
    int q = (int)(idx & 7);
    int batch = (int)(row & 127);
    float lz = logZdiv[batch];
    float4v* pp = (float4v*)(out + row * NOUT + 8 + q * 4);
    float4v vv = *pp;
    vv[0] -= lz; vv[1] -= lz; vv[2] -= lz; vv[3] -= lz;
    *pp = vv;
}

// ---------------------------------------------------------------- launch
extern "C" void kernel_launch(void* const* d_in, const int* in_sizes, int n_in,
                              void* d_out, int out_size, void* d_ws, size_t ws_size,
                              hipStream_t stream)
{
    const float* x = (const float*)d_in[0];   // (2000,128,256)
    const float* W = (const float*)d_in[1];   // (40,256)
    const float* b = (const float*)d_in[2];   // (40,)
    float* out = (float*)d_out;               // (2000,128,40)

    char* ws = (char*)d_ws;
    float* chunkM  = (float*)ws;                                      // 128*80*64*4 = 2621440 B
    float* logZdiv = (float*)(ws + (size_t)NBATCH * CCHUNK * 64 * 4);

    hipLaunchKernelGGL(gemm_act,    dim3(NROWS/128), dim3(256), 0, stream, x, W, b, out);
    hipLaunchKernelGGL(scan_chunks, dim3(CCHUNK*4),  dim3(256), 0, stream, out, chunkM);
    hipLaunchKernelGGL(combine_k,   dim3(4),         dim3(256), 0, stream, chunkM, logZdiv);
    hipLaunchKernelGGL(sub_logz,    dim3(8000),      dim3(256), 0, stream, out, logZdiv);
}